// Round 1
// baseline (291.113 us; speedup 1.0000x reference)
//
#include <hip/hip_runtime.h>

// CRF negative mean log-likelihood, B=64, T=512, U=256.
//
// Design (see analysis): one workgroup per batch element (64 WGs x 512 thr),
// forward recursion as bf16 MFMA matvec with E=exp(trans) resident in
// registers, ea staged in a double-buffered 1KB LDS buffer, ONE raw s_barrier
// per step, deferred max-rescale every 8 steps, pot register-prefetched 4
// steps ahead. unary/binary gather-scores computed block-parallel up front.

#define Bc 64
#define Tc 512
#define Uc 256
#define LOG2E 1.4426950408889634f
#define LN2   0.6931471805599453f

typedef __bf16 bf16x8 __attribute__((ext_vector_type(8)));
typedef float  f32x4  __attribute__((ext_vector_type(4)));

__device__ __forceinline__ float wave_max32(float v) {
    v = fmaxf(v, __shfl_xor(v, 1));
    v = fmaxf(v, __shfl_xor(v, 2));
    v = fmaxf(v, __shfl_xor(v, 4));
    v = fmaxf(v, __shfl_xor(v, 8));
    v = fmaxf(v, __shfl_xor(v, 16));
    return v;
}
__device__ __forceinline__ float wave_sum32(float v) {
    v += __shfl_xor(v, 1);
    v += __shfl_xor(v, 2);
    v += __shfl_xor(v, 4);
    v += __shfl_xor(v, 8);
    v += __shfl_xor(v, 16);
    return v;
}

// Raw barrier: does NOT drain vmcnt (keeps pot prefetch loads in flight,
// m218-verified behavior). lgkmcnt(0) makes our ds_write visible first.
__device__ __forceinline__ void wg_barrier() {
    asm volatile("s_waitcnt lgkmcnt(0)" ::: "memory");
    __builtin_amdgcn_s_barrier();
    asm volatile("" ::: "memory");
}

__global__ __launch_bounds__(512)
void crf_fwd(const float* __restrict__ pot, const int* __restrict__ tags,
             const int* __restrict__ seqlen, const float* __restrict__ trans,
             float* __restrict__ ws)
{
    const int b    = blockIdx.x;
    const int tid  = threadIdx.x;
    const int lane = tid & 63;
    const int w    = tid >> 6;          // wave 0..7
    const int g4   = lane >> 4;         // k-group 0..3
    const int c16  = lane & 15;         // fragment column
    const int L    = seqlen[b];

    __shared__ __align__(16) __bf16 ea_lds[2][Uc];
    __shared__ float wred[8];
    __shared__ float redU[8], redB[8];

    const float* potb = pot  + (size_t)b * Tc * Uc;
    const int*   tagb = tags + b * Tc;

    // ---- B fragments: E = exp(trans), bf16, resident in registers ----
    // wave w owns n-tiles {2w, 2w+1} (u in [32w, 32w+32)).
    // elem e of lane l = E[32*kt + 8*g4 + e][u]  -- same placement convention
    // used for A, so any hardware k-permutation cancels.
    bf16x8 bfr[8][2];
    #pragma unroll
    for (int kt = 0; kt < 8; ++kt) {
        #pragma unroll
        for (int nt = 0; nt < 2; ++nt) {
            const int u = 32 * w + 16 * nt + c16;
            bf16x8 bb;
            #pragma unroll
            for (int e = 0; e < 8; ++e) {
                const int v = 32 * kt + 8 * g4 + e;
                bb[e] = (__bf16)__builtin_exp2f(trans[v * Uc + u] * LOG2E);
            }
            bfr[kt][nt] = bb;
        }
    }

    // ---- prologue: unary + binary scores, block-parallel over t ----
    {
        const int t  = tid;             // 0..511
        const int tg = tagb[t];
        float up = 0.f, bp = 0.f;
        if (t < L)           up = potb[(size_t)t * Uc + tg];
        if (t >= 1 && t < L) bp = trans[tagb[t - 1] * Uc + tg];
        #pragma unroll
        for (int m = 1; m < 64; m <<= 1) {
            up += __shfl_xor(up, m);
            bp += __shfl_xor(bp, m);
        }
        if (lane == 0) { redU[w] = up; redB[w] = bp; }
    }
    __syncthreads();

    const int um = 32 * w + (lane & 31);   // owned u (lanes>=32 are duplicates)

    // pot prefetch registers, t = 1..4
    float pv0 = potb[(size_t)1 * Uc + um];
    float pv1 = potb[(size_t)2 * Uc + um];
    float pv2 = potb[(size_t)3 * Uc + um];
    float pv3 = potb[(size_t)4 * Uc + um];

    // ---- init (t = 0): ea = exp(pot0 - M), M = max pot0 ----
    float er = __builtin_exp2f(potb[um] * LOG2E);
    float M;
    {
        float m = wave_max32(er);
        if (lane == 0) wred[w] = m;
        __syncthreads();
        float g = fmaxf(fmaxf(fmaxf(wred[0], wred[1]), fmaxf(wred[2], wred[3])),
                        fmaxf(fmaxf(wred[4], wred[5]), fmaxf(wred[6], wred[7])));
        M  = LN2 * __builtin_log2f(g);
        er = er * __builtin_amdgcn_rcpf(g);
        if (lane < 32) ea_lds[0][um] = (__bf16)er;
        __syncthreads();
    }

    // One recursion step. Reads ea from ea_lds[RP], writes ea' to ea_lds[WP].
    #define STEPBODY(TT, PVC, RP, WP)                                          \
    {                                                                          \
        bf16x8 af[8];                                                          \
        const __bf16* ebase = &ea_lds[(RP)][8 * g4];                           \
        _Pragma("unroll")                                                      \
        for (int kt = 0; kt < 8; ++kt)                                         \
            af[kt] = *(const bf16x8*)(ebase + 32 * kt);                        \
        const f32x4 z = {0.f, 0.f, 0.f, 0.f};                                  \
        f32x4 c0l = z, c0h = z, c1l = z, c1h = z;                              \
        _Pragma("unroll")                                                      \
        for (int kt = 0; kt < 4; ++kt) {                                       \
            c0l = __builtin_amdgcn_mfma_f32_16x16x32_bf16(af[kt], bfr[kt][0], c0l, 0, 0, 0); \
            c1l = __builtin_amdgcn_mfma_f32_16x16x32_bf16(af[kt], bfr[kt][1], c1l, 0, 0, 0); \
        }                                                                      \
        _Pragma("unroll")                                                      \
        for (int kt = 4; kt < 8; ++kt) {                                       \
            c0h = __builtin_amdgcn_mfma_f32_16x16x32_bf16(af[kt], bfr[kt][0], c0h, 0, 0, 0); \
            c1h = __builtin_amdgcn_mfma_f32_16x16x32_bf16(af[kt], bfr[kt][1], c1h, 0, 0, 0); \
        }                                                                      \
        const float s0 = c0l[0] + c0h[0];                                      \
        const float s1 = c1l[0] + c1h[0];                                      \
        const float sv = (lane & 16) ? s1 : s0;                                \
        float ern = sv * __builtin_exp2f((PVC) * LOG2E);                       \
        if (((TT) & 7) == 0) {  /* deferred rescale, uniform branch */         \
            float m = wave_max32(ern);                                         \
            if (lane == 0) wred[w] = m;                                        \
            wg_barrier();                                                      \
            float g = fmaxf(fmaxf(fmaxf(wred[0], wred[1]), fmaxf(wred[2], wred[3])), \
                            fmaxf(fmaxf(wred[4], wred[5]), fmaxf(wred[6], wred[7]))); \
            M += LN2 * __builtin_log2f(g);                                     \
            ern *= __builtin_amdgcn_rcpf(g);                                   \
        }                                                                      \
        er = ern;                                                              \
        if (lane < 32) ea_lds[(WP)][um] = (__bf16)er;                          \
        wg_barrier();                                                          \
    }

    // ---- main recursion: t = 1 .. L-1, unrolled x4 with depth-4 prefetch ----
    int t = 1;
    for (; t + 3 < L; t += 4) {
        {
            const float pvc = pv0;
            int tn = t + 4; if (tn > Tc - 1) tn = Tc - 1;
            pv0 = potb[(size_t)tn * Uc + um];
            STEPBODY(t, pvc, (t + 1) & 1, t & 1);
        }
        {
            const float pvc = pv1;
            int tn = t + 5; if (tn > Tc - 1) tn = Tc - 1;
            pv1 = potb[(size_t)tn * Uc + um];
            STEPBODY(t + 1, pvc, t & 1, (t + 1) & 1);
        }
        {
            const float pvc = pv2;
            int tn = t + 6; if (tn > Tc - 1) tn = Tc - 1;
            pv2 = potb[(size_t)tn * Uc + um];
            STEPBODY(t + 2, pvc, (t + 1) & 1, t & 1);
        }
        {
            const float pvc = pv3;
            int tn = t + 7; if (tn > Tc - 1) tn = Tc - 1;
            pv3 = potb[(size_t)tn * Uc + um];
            STEPBODY(t + 3, pvc, t & 1, (t + 1) & 1);
        }
    }
    for (; t < L; ++t) {   // tail (< 4 steps): direct loads, small stall ok
        const float pvc = potb[(size_t)t * Uc + um];
        STEPBODY(t, pvc, (t + 1) & 1, t & 1);
    }

    // ---- epilogue: log_norm = M + log(sum_u ea[u]);  ll = U + B - logZ ----
    {
        float ssum = wave_sum32(er);
        if (lane == 0) wred[w] = ssum;
        __syncthreads();
        if (tid == 0) {
            float S = 0.f, uS = 0.f, bS = 0.f;
            #pragma unroll
            for (int i = 0; i < 8; ++i) { S += wred[i]; uS += redU[i]; bS += redB[i]; }
            const float logZ = M + LN2 * __builtin_log2f(S);
            ws[b] = uS + bS - logZ;
        }
    }
    #undef STEPBODY
}

__global__ void reduce_ll(const float* __restrict__ ws, float* __restrict__ out) {
    float v = ws[threadIdx.x];
    #pragma unroll
    for (int m = 1; m < 64; m <<= 1) v += __shfl_xor(v, m);
    if (threadIdx.x == 0) out[0] = -v * (1.0f / 64.0f);
}

extern "C" void kernel_launch(void* const* d_in, const int* in_sizes, int n_in,
                              void* d_out, int out_size, void* d_ws, size_t ws_size,
                              hipStream_t stream) {
    const float* pot   = (const float*)d_in[0];
    const int*   tags  = (const int*)d_in[1];
    const int*   slen  = (const int*)d_in[2];
    const float* trans = (const float*)d_in[3];
    float* wsf = (float*)d_ws;
    float* out = (float*)d_out;

    crf_fwd<<<Bc, 512, 0, stream>>>(pot, tags, slen, trans, wsf);
    reduce_ll<<<1, 64, 0, stream>>>(wsf, out);
}